// Round 1
// baseline (610.148 us; speedup 1.0000x reference)
//
#include <hip/hip_runtime.h>
#include <hip/hip_bf16.h>

typedef unsigned short u16;
typedef float f32x4 __attribute__((ext_vector_type(4)));
typedef __bf16 bf16x8 __attribute__((ext_vector_type(8)));

#define NB 4096     // batch rows
#define NM 16384    // memory bank rows
#define ND 256      // feature dim (K)
#define CT 160      // col tiles (20480 / 128)
#define RT 32       // row tiles (4096 / 128)

__device__ __forceinline__ u16 f2bf(float x) {
    unsigned u = __float_as_uint(x);
    u += 0x7FFF + ((u >> 16) & 1);   // round-to-nearest-even
    return (u16)(u >> 16);
}

__device__ __forceinline__ void gld_lds16(const u16* g, u16* l) {
    __builtin_amdgcn_global_load_lds((__attribute__((address_space(1))) void*)g,
                                     (__attribute__((address_space(3))) void*)l,
                                     16, 0, 0);
}

// ---- normalize f1/f2 rows -> fp32 normalized + bf16 normalized -------------
__global__ __launch_bounds__(64) void norm_feat(
    const float* __restrict__ in1, const float* __restrict__ in2,
    float* __restrict__ o1f, float* __restrict__ o2f,
    u16* __restrict__ o1b, u16* __restrict__ o2b)
{
    const float* in = blockIdx.y ? in2 : in1;
    float* of = blockIdx.y ? o2f : o1f;
    u16*   ob = blockIdx.y ? o2b : o1b;
    const int row = blockIdx.x, lane = threadIdx.x;
    float4 v = ((const float4*)(in + (size_t)row * ND))[lane];
    float ss = v.x*v.x + v.y*v.y + v.z*v.z + v.w*v.w;
    #pragma unroll
    for (int off = 1; off < 64; off <<= 1) ss += __shfl_xor(ss, off, 64);
    float inv = 1.0f / fmaxf(sqrtf(ss), 1e-12f);
    float4 o = make_float4(v.x*inv, v.y*inv, v.z*inv, v.w*inv);
    ((float4*)(of + (size_t)row * ND))[lane] = o;
    ushort4 b = make_ushort4(f2bf(o.x), f2bf(o.y), f2bf(o.z), f2bf(o.w));
    ((ushort4*)(ob + (size_t)row * ND))[lane] = b;
}

// ---- convert memory banks (already normalized) to bf16 ---------------------
__global__ __launch_bounds__(256) void bank_conv(
    const float* __restrict__ b1, const float* __restrict__ b2,
    u16* __restrict__ o1, u16* __restrict__ o2)
{
    const float* in = blockIdx.y ? b2 : b1;
    u16* out = blockIdx.y ? o2 : o1;
    size_t i = (size_t)blockIdx.x * 256 + threadIdx.x;  // float4 index
    float4 v = ((const float4*)in)[i];
    ushort4 b = make_ushort4(f2bf(v.x), f2bf(v.y), f2bf(v.z), f2bf(v.w));
    ((ushort4*)out)[i] = b;
}

// ---- fused GEMM + (sum-exp, max/argmax) epilogue ---------------------------
// grid: (160 coltiles, 32 rowtiles, 2 matmuls), block 256 (4 waves, 2x2)
__global__ __launch_bounds__(256) void gemm_nce(
    const u16* __restrict__ f1n, const u16* __restrict__ f2n,
    const u16* __restrict__ mb1n, const u16* __restrict__ mb2n,
    const float* __restrict__ scale_ptr,
    float* __restrict__ Zpart,    // [2][NB][CT]
    float* __restrict__ maxpart,  // [2][NB][128]
    int*   __restrict__ argpart)  // [2][NB][128]
{
    __shared__ __attribute__((aligned(16))) u16 As[128 * 64];
    __shared__ __attribute__((aligned(16))) u16 Bs[128 * 64];
    __shared__ float redsum[2][128];
    __shared__ float redmax[2][128];
    __shared__ int   redarg[2][128];

    const int ctile = blockIdx.x, rtile = blockIdx.y, z = blockIdx.z;
    const u16* A  = (z ? f2n : f1n) + (size_t)rtile * 128 * ND;
    const u16* Bp = (ctile < 32) ? ((z ? f1n : f2n) + (size_t)ctile * 128 * ND)
                                 : ((z ? mb1n : mb2n) + (size_t)(ctile - 32) * 128 * ND);
    const int t = threadIdx.x;
    const int wave = t >> 6, lane = t & 63;
    const int wr = wave >> 1, wc = wave & 1;
    const int lane16 = lane & 15, q = lane >> 4;
    const int srow = t >> 3;          // 0..31
    const int scol = (t & 7) * 8;     // bf16 elems

    f32x4 acc[4][4] = {};

    for (int kt = 0; kt < 4; ++kt) {
        const u16* ga = A  + (size_t)srow * ND + kt * 64 + scol;
        const u16* gb = Bp + (size_t)srow * ND + kt * 64 + scol;
        u16* la = As + t * 8;
        u16* lb = Bs + t * 8;
        #pragma unroll
        for (int ch = 0; ch < 4; ++ch) {
            gld_lds16(ga + (size_t)ch * 32 * ND, la + ch * 2048);
            gld_lds16(gb + (size_t)ch * 32 * ND, lb + ch * 2048);
        }
        __syncthreads();   // drains vmcnt (global_load_lds) before LDS reads
        #pragma unroll
        for (int kk = 0; kk < 2; ++kk) {
            bf16x8 af[4], bfr[4];
            #pragma unroll
            for (int i = 0; i < 4; ++i)
                af[i] = *(const bf16x8*)(As + (wr*64 + i*16 + lane16)*64 + kk*32 + q*8);
            #pragma unroll
            for (int j = 0; j < 4; ++j)
                bfr[j] = *(const bf16x8*)(Bs + (wc*64 + j*16 + lane16)*64 + kk*32 + q*8);
            #pragma unroll
            for (int i = 0; i < 4; ++i)
                #pragma unroll
                for (int j = 0; j < 4; ++j)
                    acc[i][j] = __builtin_amdgcn_mfma_f32_16x16x32_bf16(
                        af[i], bfr[j], acc[i][j], 0, 0, 0);
        }
        __syncthreads();
    }

    const float scale = *scale_ptr;
    const float kl = scale * 1.44269504088896f;  // scale * log2(e)

    // C/D layout (m89/m91): col = lane&15, row = q*4 + reg (within 16x16)
    #pragma unroll
    for (int i = 0; i < 4; ++i) {
        #pragma unroll
        for (int r = 0; r < 4; ++r) {
            float s0 = acc[i][0][r], s1 = acc[i][1][r], s2 = acc[i][2][r], s3 = acc[i][3][r];
            float e = exp2f(kl*s0) + exp2f(kl*s1) + exp2f(kl*s2) + exp2f(kl*s3);
            #pragma unroll
            for (int off = 1; off < 16; off <<= 1) e += __shfl_xor(e, off, 16);
            float m = s0; int a = lane16;           // col within wave = j*16+lane16
            if (s1 > m) { m = s1; a = 16 + lane16; }
            if (s2 > m) { m = s2; a = 32 + lane16; }
            if (s3 > m) { m = s3; a = 48 + lane16; }
            #pragma unroll
            for (int off = 1; off < 16; off <<= 1) {
                float om = __shfl_xor(m, off, 16);
                int   oa = __shfl_xor(a, off, 16);
                if (om > m || (om == m && oa < a)) { m = om; a = oa; }
            }
            if (lane16 == 0) {
                int rl = wr*64 + i*16 + q*4 + r;
                redsum[wc][rl] = e;
                redmax[wc][rl] = m;
                redarg[wc][rl] = wc*64 + a;
            }
        }
    }
    __syncthreads();
    if (t < 128) {
        int grow = rtile * 128 + t;
        float zs = redsum[0][t] + redsum[1][t];
        Zpart[((size_t)z * NB + grow) * CT + ctile] = zs;
        if (ctile >= 32) {
            float m0 = redmax[0][t], m1 = redmax[1][t];
            int   a0 = redarg[0][t], a1 = redarg[1][t];
            float m = m0; int a = a0;
            if (m1 > m) { m = m1; a = a1; }  // tie keeps lower (wc=0) index
            maxpart[((size_t)z * NB + grow) * 128 + (ctile - 32)] = m;
            argpart[((size_t)z * NB + grow) * 128 + (ctile - 32)] = (ctile - 32) * 128 + a;
        }
    }
}

// ---- per-row finalize: Z-sum, argmax combine, diag dot, masked MSE ---------
__global__ __launch_bounds__(256) void finalize_rows(
    const float* __restrict__ Zpart, const float* __restrict__ maxpart,
    const int* __restrict__ argpart,
    const float* __restrict__ f1f, const float* __restrict__ f2f,
    const float* __restrict__ mb1, const float* __restrict__ mb2,
    const float* __restrict__ scale_ptr, float* __restrict__ accum)
{
    const int wave = threadIdx.x >> 6, lane = threadIdx.x & 63;
    const int row = blockIdx.x * 4 + wave;

    float z1 = 0.f, z2 = 0.f;
    const float* zp1 = Zpart + (size_t)row * CT;
    const float* zp2 = Zpart + ((size_t)NB + row) * CT;
    for (int c = lane; c < CT; c += 64) { z1 += zp1[c]; z2 += zp2[c]; }
    #pragma unroll
    for (int off = 1; off < 64; off <<= 1) {
        z1 += __shfl_xor(z1, off, 64);
        z2 += __shfl_xor(z2, off, 64);
    }

    float m1 = -2.f, m2 = -2.f; int a1 = 0, a2 = 0;
    const float* mp1 = maxpart + (size_t)row * 128;
    const float* mp2 = maxpart + ((size_t)NB + row) * 128;
    const int* ap1 = argpart + (size_t)row * 128;
    const int* ap2 = argpart + ((size_t)NB + row) * 128;
    #pragma unroll
    for (int c0 = 0; c0 < 128; c0 += 64) {
        int c = c0 + lane;
        float mv = mp1[c]; int av = ap1[c];
        if (mv > m1 || (mv == m1 && av < a1)) { m1 = mv; a1 = av; }
        mv = mp2[c]; av = ap2[c];
        if (mv > m2 || (mv == m2 && av < a2)) { m2 = mv; a2 = av; }
    }
    #pragma unroll
    for (int off = 1; off < 64; off <<= 1) {
        float om = __shfl_xor(m1, off, 64); int oa = __shfl_xor(a1, off, 64);
        if (om > m1 || (om == m1 && oa < a1)) { m1 = om; a1 = oa; }
        om = __shfl_xor(m2, off, 64); oa = __shfl_xor(a2, off, 64);
        if (om > m2 || (om == m2 && oa < a2)) { m2 = om; a2 = oa; }
    }

    float4 x1 = ((const float4*)(f1f + (size_t)row * ND))[lane];
    float4 x2 = ((const float4*)(f2f + (size_t)row * ND))[lane];
    float d = x1.x*x2.x + x1.y*x2.y + x1.z*x2.z + x1.w*x2.w;
    float4 y1 = ((const float4*)(mb2 + (size_t)a1 * ND))[lane];
    float4 y2 = ((const float4*)(mb1 + (size_t)a2 * ND))[lane];
    float dx = x1.x - y1.x, dy = x1.y - y1.y, dz = x1.z - y1.z, dw = x1.w - y1.w;
    float sq1 = dx*dx + dy*dy + dz*dz + dw*dw;
    dx = x2.x - y2.x; dy = x2.y - y2.y; dz = x2.z - y2.z; dw = x2.w - y2.w;
    float sq2 = dx*dx + dy*dy + dz*dz + dw*dw;
    #pragma unroll
    for (int off = 1; off < 64; off <<= 1) {
        d   += __shfl_xor(d,   off, 64);
        sq1 += __shfl_xor(sq1, off, 64);
        sq2 += __shfl_xor(sq2, off, 64);
    }
    if (lane == 0) {
        float scale = *scale_ptr;
        float ce = logf(z1) + logf(z2) - 2.f * scale * d;
        atomicAdd(&accum[0], ce);
        if (m1 > 0.2f) { atomicAdd(&accum[1], sq1); atomicAdd(&accum[2], 1.f); }
        if (m2 > 0.2f) { atomicAdd(&accum[3], sq2); atomicAdd(&accum[4], 1.f); }
    }
}

__global__ void final_out(const float* __restrict__ accum, float* __restrict__ out) {
    float nce = 0.5f * accum[0] / (float)NB;
    float icel1 = accum[2] > 0.f ? accum[1] / (accum[2] * (float)ND) : 0.f;
    float icel2 = accum[4] > 0.f ? accum[3] / (accum[4] * (float)ND) : 0.f;
    out[0] = nce + 0.5f * (0.5f * (icel1 + icel2));   // LAMBDA_ICEL = 0.5
}

extern "C" void kernel_launch(void* const* d_in, const int* in_sizes, int n_in,
                              void* d_out, int out_size, void* d_ws, size_t ws_size,
                              hipStream_t stream) {
    const float* if1   = (const float*)d_in[0];
    const float* if2   = (const float*)d_in[1];
    const float* scale = (const float*)d_in[2];
    const float* mb1   = (const float*)d_in[3];
    const float* mb2   = (const float*)d_in[4];
    float* out = (float*)d_out;

    unsigned char* w = (unsigned char*)d_ws;
    size_t off = 0;
    auto alloc = [&](size_t bytes) {
        void* p = w + off;
        off += (bytes + 255) & ~(size_t)255;
        return p;
    };
    u16*   f1n     = (u16*)  alloc((size_t)NB * ND * 2);
    u16*   f2n     = (u16*)  alloc((size_t)NB * ND * 2);
    u16*   mb1n    = (u16*)  alloc((size_t)NM * ND * 2);
    u16*   mb2n    = (u16*)  alloc((size_t)NM * ND * 2);
    float* f1f     = (float*)alloc((size_t)NB * ND * 4);
    float* f2f     = (float*)alloc((size_t)NB * ND * 4);
    float* Zpart   = (float*)alloc((size_t)2 * NB * CT * 4);
    float* maxpart = (float*)alloc((size_t)2 * NB * 128 * 4);
    int*   argpart = (int*)  alloc((size_t)2 * NB * 128 * 4);
    float* accum   = (float*)alloc(256);

    hipMemsetAsync(accum, 0, 32, stream);
    norm_feat<<<dim3(NB, 2), 64, 0, stream>>>(if1, if2, f1f, f2f, f1n, f2n);
    bank_conv<<<dim3((NM * ND / 4) / 256, 2), 256, 0, stream>>>(mb1, mb2, mb1n, mb2n);
    gemm_nce<<<dim3(CT, RT, 2), 256, 0, stream>>>(f1n, f2n, mb1n, mb2n, scale,
                                                  Zpart, maxpart, argpart);
    finalize_rows<<<dim3(NB / 4), 256, 0, stream>>>(Zpart, maxpart, argpart,
                                                    f1f, f2f, mb1, mb2, scale, accum);
    final_out<<<1, 1, 0, stream>>>(accum, out);
}

// Round 2
// 325.177 us; speedup vs baseline: 1.8764x; 1.8764x over previous
//
#include <hip/hip_runtime.h>
#include <hip/hip_bf16.h>

typedef unsigned short u16;
typedef float f32x4 __attribute__((ext_vector_type(4)));
typedef __bf16 bf16x8 __attribute__((ext_vector_type(8)));

#define NB 4096     // batch rows
#define NM 16384    // memory bank rows
#define ND 256      // feature dim (K)
#define CT 160      // col tiles (20480 / 128)
#define RT 32       // row tiles (4096 / 128)

__device__ __forceinline__ u16 f2bf(float x) {
    unsigned u = __float_as_uint(x);
    u += 0x7FFF + ((u >> 16) & 1);   // round-to-nearest-even
    return (u16)(u >> 16);
}

__device__ __forceinline__ void gld_lds16(const u16* g, u16* l) {
    __builtin_amdgcn_global_load_lds((__attribute__((address_space(1))) void*)g,
                                     (__attribute__((address_space(3))) void*)l,
                                     16, 0, 0);
}

// ---- normalize f1/f2 rows -> fp32 normalized + bf16 normalized -------------
__global__ __launch_bounds__(64) void norm_feat(
    const float* __restrict__ in1, const float* __restrict__ in2,
    float* __restrict__ o1f, float* __restrict__ o2f,
    u16* __restrict__ o1b, u16* __restrict__ o2b)
{
    const float* in = blockIdx.y ? in2 : in1;
    float* of = blockIdx.y ? o2f : o1f;
    u16*   ob = blockIdx.y ? o2b : o1b;
    const int row = blockIdx.x, lane = threadIdx.x;
    float4 v = ((const float4*)(in + (size_t)row * ND))[lane];
    float ss = v.x*v.x + v.y*v.y + v.z*v.z + v.w*v.w;
    #pragma unroll
    for (int off = 1; off < 64; off <<= 1) ss += __shfl_xor(ss, off, 64);
    float inv = 1.0f / fmaxf(sqrtf(ss), 1e-12f);
    float4 o = make_float4(v.x*inv, v.y*inv, v.z*inv, v.w*inv);
    ((float4*)(of + (size_t)row * ND))[lane] = o;
    ushort4 b = make_ushort4(f2bf(o.x), f2bf(o.y), f2bf(o.z), f2bf(o.w));
    ((ushort4*)(ob + (size_t)row * ND))[lane] = b;
}

// ---- convert memory banks (already normalized) to bf16 ---------------------
__global__ __launch_bounds__(256) void bank_conv(
    const float* __restrict__ b1, const float* __restrict__ b2,
    u16* __restrict__ o1, u16* __restrict__ o2)
{
    const float* in = blockIdx.y ? b2 : b1;
    u16* out = blockIdx.y ? o2 : o1;
    size_t i = (size_t)blockIdx.x * 256 + threadIdx.x;  // float4 index
    float4 v = ((const float4*)in)[i];
    ushort4 b = make_ushort4(f2bf(v.x), f2bf(v.y), f2bf(v.z), f2bf(v.w));
    ((ushort4*)out)[i] = b;
}

// ---- fused GEMM + (sum-exp, max/argmax) epilogue ---------------------------
// grid: (160 coltiles, 32 rowtiles, 2 matmuls), block 256 (4 waves, 2x2)
// LDS layout XOR-swizzled: 16B chunk at (row, slot cs) holds global chunk
// cs ^ (row & 7)  -> fragment reads hit all 32 banks per 8-lane group.
__global__ __launch_bounds__(256) void gemm_nce(
    const u16* __restrict__ f1n, const u16* __restrict__ f2n,
    const u16* __restrict__ mb1n, const u16* __restrict__ mb2n,
    const float* __restrict__ scale_ptr,
    float* __restrict__ Zpart,    // [2][CT][NB]
    float* __restrict__ maxpart,  // [2][128][NB]
    int*   __restrict__ argpart)  // [2][128][NB]
{
    __shared__ __attribute__((aligned(16))) u16 As[128 * 64];
    __shared__ __attribute__((aligned(16))) u16 Bs[128 * 64];
    __shared__ float redsum[2][128];
    __shared__ float redmax[2][128];
    __shared__ int   redarg[2][128];

    const int ctile = blockIdx.x, rtile = blockIdx.y, z = blockIdx.z;
    const u16* A  = (z ? f2n : f1n) + (size_t)rtile * 128 * ND;
    const u16* Bp = (ctile < 32) ? ((z ? f1n : f2n) + (size_t)ctile * 128 * ND)
                                 : ((z ? mb1n : mb2n) + (size_t)(ctile - 32) * 128 * ND);
    const int t = threadIdx.x;
    const int wave = t >> 6, lane = t & 63;
    const int wr = wave >> 1, wc = wave & 1;
    const int lane16 = lane & 15, q = lane >> 4;
    const int srow = t >> 3;                        // 0..31 staged row
    const int cg = (t & 7) ^ ((t >> 3) & 7);        // swizzled global chunk

    f32x4 acc[4][4] = {};

    for (int kt = 0; kt < 4; ++kt) {
        const u16* ga = A  + (size_t)srow * ND + kt * 64 + cg * 8;
        const u16* gb = Bp + (size_t)srow * ND + kt * 64 + cg * 8;
        u16* la = As + t * 8;
        u16* lb = Bs + t * 8;
        #pragma unroll
        for (int ch = 0; ch < 4; ++ch) {
            gld_lds16(ga + (size_t)ch * 32 * ND, la + ch * 2048);
            gld_lds16(gb + (size_t)ch * 32 * ND, lb + ch * 2048);
        }
        __syncthreads();   // drains vmcnt (global_load_lds) before LDS reads
        #pragma unroll
        for (int kk = 0; kk < 2; ++kk) {
            bf16x8 af[4], bfr[4];
            const int sw = (kk * 4 + q) ^ (lane16 & 7);   // swizzled chunk slot
            #pragma unroll
            for (int i = 0; i < 4; ++i)
                af[i] = *(const bf16x8*)(As + (wr*64 + i*16 + lane16)*64 + sw*8);
            #pragma unroll
            for (int j = 0; j < 4; ++j)
                bfr[j] = *(const bf16x8*)(Bs + (wc*64 + j*16 + lane16)*64 + sw*8);
            #pragma unroll
            for (int i = 0; i < 4; ++i)
                #pragma unroll
                for (int j = 0; j < 4; ++j)
                    acc[i][j] = __builtin_amdgcn_mfma_f32_16x16x32_bf16(
                        af[i], bfr[j], acc[i][j], 0, 0, 0);
        }
        __syncthreads();
    }

    const float scale = *scale_ptr;
    const float kl = scale * 1.44269504088896f;  // scale * log2(e)

    // C/D layout (m89/m91): col = lane&15, row = q*4 + reg (within 16x16)
    #pragma unroll
    for (int i = 0; i < 4; ++i) {
        #pragma unroll
        for (int r = 0; r < 4; ++r) {
            float s0 = acc[i][0][r], s1 = acc[i][1][r], s2 = acc[i][2][r], s3 = acc[i][3][r];
            float e = exp2f(kl*s0) + exp2f(kl*s1) + exp2f(kl*s2) + exp2f(kl*s3);
            #pragma unroll
            for (int off = 1; off < 16; off <<= 1) e += __shfl_xor(e, off, 16);
            float m = s0; int a = lane16;           // col within wave = j*16+lane16
            if (s1 > m) { m = s1; a = 16 + lane16; }
            if (s2 > m) { m = s2; a = 32 + lane16; }
            if (s3 > m) { m = s3; a = 48 + lane16; }
            #pragma unroll
            for (int off = 1; off < 16; off <<= 1) {
                float om = __shfl_xor(m, off, 16);
                int   oa = __shfl_xor(a, off, 16);
                if (om > m || (om == m && oa < a)) { m = om; a = oa; }
            }
            if (lane16 == 0) {
                int rl = wr*64 + i*16 + q*4 + r;
                redsum[wc][rl] = e;
                redmax[wc][rl] = m;
                redarg[wc][rl] = wc*64 + a;
            }
        }
    }
    __syncthreads();
    if (t < 128) {
        int grow = rtile * 128 + t;
        float zs = redsum[0][t] + redsum[1][t];
        Zpart[((size_t)z * CT + ctile) * NB + grow] = zs;   // coalesced over t
        if (ctile >= 32) {
            float m0 = redmax[0][t], m1 = redmax[1][t];
            int   a0 = redarg[0][t], a1 = redarg[1][t];
            float m = m0; int a = a0;
            if (m1 > m) { m = m1; a = a1; }  // tie keeps lower (wc=0) index
            size_t idx = ((size_t)z * 128 + (ctile - 32)) * NB + grow;
            maxpart[idx] = m;
            argpart[idx] = (ctile - 32) * 128 + a;
        }
    }
}

// ---- per-row reduction over column tiles (all loads coalesced) -------------
// grid (NB/64, 2), block 256: 64 rows per block, 4 waves split the c-range.
__global__ __launch_bounds__(256) void reduce_rows(
    const float* __restrict__ Zpart, const float* __restrict__ maxpart,
    const int* __restrict__ argpart,
    float* __restrict__ Zrow, float* __restrict__ Mrow, int* __restrict__ Arow)
{
    __shared__ float zls[4][64];
    __shared__ float mls[4][64];
    __shared__ int   als[4][64];
    const int z = blockIdx.y;
    const int w = threadIdx.x >> 6, l = threadIdx.x & 63;
    const int row = blockIdx.x * 64 + l;

    float zs = 0.f;
    const float* zp = Zpart + (size_t)z * CT * NB + row;
    #pragma unroll 4
    for (int c = w * 40; c < w * 40 + 40; ++c) zs += zp[(size_t)c * NB];

    float m = -2.f; int a = 0;
    const float* mp = maxpart + (size_t)z * 128 * NB + row;
    const int*   ap = argpart + (size_t)z * 128 * NB + row;
    #pragma unroll 4
    for (int c = w * 32; c < w * 32 + 32; ++c) {
        float v = mp[(size_t)c * NB];
        if (v > m) { m = v; a = ap[(size_t)c * NB]; }
    }
    zls[w][l] = zs; mls[w][l] = m; als[w][l] = a;
    __syncthreads();
    if (w == 0) {
        float zt = zls[0][l] + zls[1][l] + zls[2][l] + zls[3][l];
        float mt = mls[0][l]; int at = als[0][l];
        #pragma unroll
        for (int k = 1; k < 4; ++k)   // ascending c-quarters; strict > keeps lowest idx
            if (mls[k][l] > mt) { mt = mls[k][l]; at = als[k][l]; }
        Zrow[z * NB + row] = zt;
        Mrow[z * NB + row] = mt;
        Arow[z * NB + row] = at;
    }
}

// ---- per-row finalize: diag dot + masked MSE; block partials (no atomics) --
// grid NB/4, block 256 (wave per row). Bpart layout [5][NB/4].
__global__ __launch_bounds__(256) void finalize2(
    const float* __restrict__ Zrow, const float* __restrict__ Mrow,
    const int* __restrict__ Arow,
    const float* __restrict__ f1f, const float* __restrict__ f2f,
    const float* __restrict__ mb1, const float* __restrict__ mb2,
    const float* __restrict__ scale_ptr, float* __restrict__ Bpart)
{
    __shared__ float lds[5][4];
    const int wave = threadIdx.x >> 6, lane = threadIdx.x & 63;
    const int row = blockIdx.x * 4 + wave;

    float z1 = Zrow[row], z2 = Zrow[NB + row];
    float m1 = Mrow[row], m2 = Mrow[NB + row];
    int   a1 = Arow[row], a2 = Arow[NB + row];

    float4 x1 = ((const float4*)(f1f + (size_t)row * ND))[lane];
    float4 x2 = ((const float4*)(f2f + (size_t)row * ND))[lane];
    float d = x1.x*x2.x + x1.y*x2.y + x1.z*x2.z + x1.w*x2.w;
    float4 y1 = ((const float4*)(mb2 + (size_t)a1 * ND))[lane];
    float4 y2 = ((const float4*)(mb1 + (size_t)a2 * ND))[lane];
    float dx = x1.x - y1.x, dy = x1.y - y1.y, dz = x1.z - y1.z, dw = x1.w - y1.w;
    float sq1 = dx*dx + dy*dy + dz*dz + dw*dw;
    dx = x2.x - y2.x; dy = x2.y - y2.y; dz = x2.z - y2.z; dw = x2.w - y2.w;
    float sq2 = dx*dx + dy*dy + dz*dz + dw*dw;
    #pragma unroll
    for (int off = 1; off < 64; off <<= 1) {
        d   += __shfl_xor(d,   off, 64);
        sq1 += __shfl_xor(sq1, off, 64);
        sq2 += __shfl_xor(sq2, off, 64);
    }
    if (lane == 0) {
        float scale = *scale_ptr;
        lds[0][wave] = logf(z1) + logf(z2) - 2.f * scale * d;
        lds[1][wave] = (m1 > 0.2f) ? sq1 : 0.f;
        lds[2][wave] = (m1 > 0.2f) ? 1.f : 0.f;
        lds[3][wave] = (m2 > 0.2f) ? sq2 : 0.f;
        lds[4][wave] = (m2 > 0.2f) ? 1.f : 0.f;
    }
    __syncthreads();
    if (threadIdx.x < 5) {
        int k = threadIdx.x;
        Bpart[(size_t)k * (NB/4) + blockIdx.x] =
            lds[k][0] + lds[k][1] + lds[k][2] + lds[k][3];
    }
}

__global__ __launch_bounds__(256) void final_out(
    const float* __restrict__ Bpart, float* __restrict__ out)
{
    __shared__ float red[5][4];
    const int wave = threadIdx.x >> 6, lane = threadIdx.x & 63;
    float s[5];
    #pragma unroll
    for (int k = 0; k < 5; ++k) {
        float v = 0.f;
        for (int i = threadIdx.x; i < NB/4; i += 256)
            v += Bpart[(size_t)k * (NB/4) + i];
        #pragma unroll
        for (int off = 1; off < 64; off <<= 1) v += __shfl_xor(v, off, 64);
        s[k] = v;
    }
    if (lane == 0)
        #pragma unroll
        for (int k = 0; k < 5; ++k) red[k][wave] = s[k];
    __syncthreads();
    if (threadIdx.x == 0) {
        float a[5];
        #pragma unroll
        for (int k = 0; k < 5; ++k)
            a[k] = red[k][0] + red[k][1] + red[k][2] + red[k][3];
        float nce = 0.5f * a[0] / (float)NB;
        float icel1 = a[2] > 0.f ? a[1] / (a[2] * (float)ND) : 0.f;
        float icel2 = a[4] > 0.f ? a[3] / (a[4] * (float)ND) : 0.f;
        out[0] = nce + 0.5f * (0.5f * (icel1 + icel2));   // LAMBDA_ICEL = 0.5
    }
}

extern "C" void kernel_launch(void* const* d_in, const int* in_sizes, int n_in,
                              void* d_out, int out_size, void* d_ws, size_t ws_size,
                              hipStream_t stream) {
    const float* if1   = (const float*)d_in[0];
    const float* if2   = (const float*)d_in[1];
    const float* scale = (const float*)d_in[2];
    const float* mb1   = (const float*)d_in[3];
    const float* mb2   = (const float*)d_in[4];
    float* out = (float*)d_out;

    unsigned char* w = (unsigned char*)d_ws;
    size_t off = 0;
    auto alloc = [&](size_t bytes) {
        void* p = w + off;
        off += (bytes + 255) & ~(size_t)255;
        return p;
    };
    u16*   f1n     = (u16*)  alloc((size_t)NB * ND * 2);
    u16*   f2n     = (u16*)  alloc((size_t)NB * ND * 2);
    u16*   mb1n    = (u16*)  alloc((size_t)NM * ND * 2);
    u16*   mb2n    = (u16*)  alloc((size_t)NM * ND * 2);
    float* f1f     = (float*)alloc((size_t)NB * ND * 4);
    float* f2f     = (float*)alloc((size_t)NB * ND * 4);
    float* Zpart   = (float*)alloc((size_t)2 * CT * NB * 4);
    float* maxpart = (float*)alloc((size_t)2 * 128 * NB * 4);
    int*   argpart = (int*)  alloc((size_t)2 * 128 * NB * 4);
    float* Zrow    = (float*)alloc((size_t)2 * NB * 4);
    float* Mrow    = (float*)alloc((size_t)2 * NB * 4);
    int*   Arow    = (int*)  alloc((size_t)2 * NB * 4);
    float* Bpart   = (float*)alloc((size_t)5 * (NB/4) * 4);

    norm_feat<<<dim3(NB, 2), 64, 0, stream>>>(if1, if2, f1f, f2f, f1n, f2n);
    bank_conv<<<dim3((NM * ND / 4) / 256, 2), 256, 0, stream>>>(mb1, mb2, mb1n, mb2n);
    gemm_nce<<<dim3(CT, RT, 2), 256, 0, stream>>>(f1n, f2n, mb1n, mb2n, scale,
                                                  Zpart, maxpart, argpart);
    reduce_rows<<<dim3(NB/64, 2), 256, 0, stream>>>(Zpart, maxpart, argpart,
                                                    Zrow, Mrow, Arow);
    finalize2<<<dim3(NB/4), 256, 0, stream>>>(Zrow, Mrow, Arow,
                                              f1f, f2f, mb1, mb2, scale, Bpart);
    final_out<<<1, 256, 0, stream>>>(Bpart, out);
}

// Round 3
// 299.846 us; speedup vs baseline: 2.0349x; 1.0845x over previous
//
#include <hip/hip_runtime.h>
#include <hip/hip_bf16.h>

typedef unsigned short u16;
typedef float f32x4 __attribute__((ext_vector_type(4)));
typedef __bf16 bf16x8 __attribute__((ext_vector_type(8)));

#define NB 4096     // batch rows
#define NM 16384    // memory bank rows
#define ND 256      // feature dim (K)
#define CT 160      // col tiles (20480 / 128)
#define RT 32       // row tiles (4096 / 128)

__device__ __forceinline__ u16 f2bf(float x) {
    unsigned u = __float_as_uint(x);
    u += 0x7FFF + ((u >> 16) & 1);   // round-to-nearest-even
    return (u16)(u >> 16);
}

__device__ __forceinline__ void gld_lds16(const u16* g, u16* l) {
    __builtin_amdgcn_global_load_lds((__attribute__((address_space(1))) void*)g,
                                     (__attribute__((address_space(3))) void*)l,
                                     16, 0, 0);
}

// ---- fused prep: normalize f1/f2 (fp32+bf16 out), convert banks to bf16 ----
// blocks 0..2047: norm (4 rows each, wave per row). blocks 2048..10239: conv.
__global__ __launch_bounds__(256) void prep(
    const float* __restrict__ if1, const float* __restrict__ if2,
    const float* __restrict__ mb1, const float* __restrict__ mb2,
    float* __restrict__ f1f, float* __restrict__ f2f,
    u16* __restrict__ f1n, u16* __restrict__ f2n,
    u16* __restrict__ mb1n, u16* __restrict__ mb2n,
    float* __restrict__ accum)
{
    const int b = blockIdx.x, t = threadIdx.x;
    if (b == 0 && t < 8) accum[t] = 0.f;   // zero sums + counter
    if (b < 2048) {
        const int wave = t >> 6, lane = t & 63;
        const int g = b * 4 + wave;         // 0..8191
        const float* in; float* of; u16* ob; int row;
        if (g < NB) { in = if1; of = f1f; ob = f1n; row = g; }
        else        { in = if2; of = f2f; ob = f2n; row = g - NB; }
        float4 v = ((const float4*)(in + (size_t)row * ND))[lane];
        float ss = v.x*v.x + v.y*v.y + v.z*v.z + v.w*v.w;
        #pragma unroll
        for (int off = 1; off < 64; off <<= 1) ss += __shfl_xor(ss, off, 64);
        float inv = 1.0f / fmaxf(sqrtf(ss), 1e-12f);
        float4 o = make_float4(v.x*inv, v.y*inv, v.z*inv, v.w*inv);
        ((float4*)(of + (size_t)row * ND))[lane] = o;
        ushort4 bb = make_ushort4(f2bf(o.x), f2bf(o.y), f2bf(o.z), f2bf(o.w));
        ((ushort4*)(ob + (size_t)row * ND))[lane] = bb;
    } else {
        size_t i = (size_t)(b - 2048) * 256 + t;      // float4 index, 0..2M
        const float* in; u16* ob; size_t idx;
        if (i < (size_t)NM * 64) { in = mb1; ob = mb1n; idx = i; }
        else { in = mb2; ob = mb2n; idx = i - (size_t)NM * 64; }
        float4 v = ((const float4*)in)[idx];
        ushort4 bb = make_ushort4(f2bf(v.x), f2bf(v.y), f2bf(v.z), f2bf(v.w));
        ((ushort4*)ob)[idx] = bb;
    }
}

// ---- fused GEMM + (sum-exp, packed max/argmax) epilogue --------------------
// grid: (160 coltiles, 32 rowtiles, 2 matmuls), block 256 (4 waves, 2x2)
// LDS XOR-swizzled: chunk at (row, slot cs) holds global chunk cs ^ (row&7).
__global__ __launch_bounds__(256) void gemm_nce(
    const u16* __restrict__ f1n, const u16* __restrict__ f2n,
    const u16* __restrict__ mb1n, const u16* __restrict__ mb2n,
    const float* __restrict__ scale_ptr,
    float* __restrict__ Zpart,    // [2][CT][NB]
    float* __restrict__ maxpart,  // [2][128][NB]
    int*   __restrict__ argpart)  // [2][128][NB]
{
    __shared__ __attribute__((aligned(16))) u16 As[128 * 64];
    __shared__ __attribute__((aligned(16))) u16 Bs[128 * 64];
    __shared__ float    redsum[2][128];
    __shared__ unsigned redpak[2][128];

    const int ctile = blockIdx.x, rtile = blockIdx.y, z = blockIdx.z;
    const u16* A  = (z ? f2n : f1n) + (size_t)rtile * 128 * ND;
    const u16* Bp = (ctile < 32) ? ((z ? f1n : f2n) + (size_t)ctile * 128 * ND)
                                 : ((z ? mb1n : mb2n) + (size_t)(ctile - 32) * 128 * ND);
    const int t = threadIdx.x;
    const int wave = t >> 6, lane = t & 63;
    const int wr = wave >> 1, wc = wave & 1;
    const int lane16 = lane & 15, q = lane >> 4;
    const int srow = t >> 3;                        // 0..31 staged row
    const int cg = (t & 7) ^ ((t >> 3) & 7);        // swizzled global chunk

    f32x4 acc[4][4] = {};

    #pragma unroll
    for (int kt = 0; kt < 4; ++kt) {
        const u16* ga = A  + (size_t)srow * ND + kt * 64 + cg * 8;
        const u16* gb = Bp + (size_t)srow * ND + kt * 64 + cg * 8;
        u16* la = As + t * 8;
        u16* lb = Bs + t * 8;
        #pragma unroll
        for (int ch = 0; ch < 4; ++ch) {
            gld_lds16(ga + (size_t)ch * 32 * ND, la + ch * 2048);
            gld_lds16(gb + (size_t)ch * 32 * ND, lb + ch * 2048);
        }
        __syncthreads();   // drains vmcnt (global_load_lds) before LDS reads
        #pragma unroll
        for (int kk = 0; kk < 2; ++kk) {
            bf16x8 af[4], bfr[4];
            const int sw = (kk * 4 + q) ^ (lane16 & 7);   // swizzled chunk slot
            #pragma unroll
            for (int i = 0; i < 4; ++i)
                af[i] = *(const bf16x8*)(As + (wr*64 + i*16 + lane16)*64 + sw*8);
            #pragma unroll
            for (int j = 0; j < 4; ++j)
                bfr[j] = *(const bf16x8*)(Bs + (wc*64 + j*16 + lane16)*64 + sw*8);
            #pragma unroll
            for (int i = 0; i < 4; ++i)
                #pragma unroll
                for (int j = 0; j < 4; ++j)
                    acc[i][j] = __builtin_amdgcn_mfma_f32_16x16x32_bf16(
                        af[i], bfr[j], acc[i][j], 0, 0, 0);
        }
        __syncthreads();
    }

    const float scale = *scale_ptr;
    const float kl = scale * 1.44269504088896f;  // scale * log2(e)

    // Monotone pack: s+3 clamped to [2,4) => exponent fixed at 128, mantissa
    // order-isomorphic to value. packed = (as_uint << 7) | (127 - col):
    // umax picks larger value, then LOWER column (first-index tie-break).
    unsigned cpack[4];
    #pragma unroll
    for (int j = 0; j < 4; ++j) cpack[j] = 127 - (j * 16 + lane16);

    // C/D layout (m89/m91): col = lane&15, row = q*4 + reg (within 16x16)
    #pragma unroll
    for (int i = 0; i < 4; ++i) {
        #pragma unroll
        for (int r = 0; r < 4; ++r) {
            float s0 = acc[i][0][r], s1 = acc[i][1][r], s2 = acc[i][2][r], s3 = acc[i][3][r];
            float e = exp2f(kl*s0) + exp2f(kl*s1) + exp2f(kl*s2) + exp2f(kl*s3);
            #pragma unroll
            for (int off = 1; off < 16; off <<= 1) e += __shfl_xor(e, off, 16);
            unsigned p0 = (__float_as_uint(fminf(fmaxf(s0 + 3.0f, 2.0f), 3.9999998f)) << 7) | cpack[0];
            unsigned p1 = (__float_as_uint(fminf(fmaxf(s1 + 3.0f, 2.0f), 3.9999998f)) << 7) | cpack[1];
            unsigned p2 = (__float_as_uint(fminf(fmaxf(s2 + 3.0f, 2.0f), 3.9999998f)) << 7) | cpack[2];
            unsigned p3 = (__float_as_uint(fminf(fmaxf(s3 + 3.0f, 2.0f), 3.9999998f)) << 7) | cpack[3];
            unsigned p = max(max(p0, p1), max(p2, p3));
            #pragma unroll
            for (int off = 1; off < 16; off <<= 1)
                p = max(p, (unsigned)__shfl_xor((int)p, off, 16));
            if (lane16 == 0) {
                int rl = wr*64 + i*16 + q*4 + r;
                redsum[wc][rl] = e;
                redpak[wc][rl] = p;
            }
        }
    }
    __syncthreads();
    if (t < 128) {
        int grow = rtile * 128 + t;
        float zs = redsum[0][t] + redsum[1][t];
        Zpart[((size_t)z * CT + ctile) * NB + grow] = zs;   // coalesced over t
        if (ctile >= 32) {
            unsigned q0 = redpak[0][t], q1 = redpak[1][t];
            float m0 = __uint_as_float(0x40000000u | (q0 >> 7)) - 3.0f;  // lossless
            float m1 = __uint_as_float(0x40000000u | (q1 >> 7)) - 3.0f;
            int c0 = 127 - (int)(q0 & 127);   // 0..63 within wc half
            int c1 = 127 - (int)(q1 & 127);
            float m = m0; int a = c0;
            if (m1 > m) { m = m1; a = 64 + c1; }  // strict >: tie keeps lower col
            size_t idx = ((size_t)z * 128 + (ctile - 32)) * NB + grow;
            maxpart[idx] = m;
            argpart[idx] = (ctile - 32) * 128 + a;
        }
    }
}

// ---- fused reduce + finalize + combine (single launch, atomic counter) -----
// grid 64 blocks x 256: block handles 64 rows for BOTH z.
__global__ __launch_bounds__(256) void reduce_final(
    const float* __restrict__ Zpart, const float* __restrict__ maxpart,
    const int* __restrict__ argpart,
    const float* __restrict__ f1f, const float* __restrict__ f2f,
    const float* __restrict__ mb1, const float* __restrict__ mb2,
    const float* __restrict__ scale_ptr, float* __restrict__ accum,
    float* __restrict__ out)
{
    __shared__ float zls[2][4][64];
    __shared__ float mls[2][4][64];
    __shared__ int   als[2][4][64];
    __shared__ float Zr[2][64], Mr[2][64];
    __shared__ int   Ar[2][64];
    __shared__ float lds5[64][5];

    const int t = threadIdx.x, w = t >> 6, l = t & 63;
    const int base = blockIdx.x * 64;

    #pragma unroll
    for (int z = 0; z < 2; ++z) {
        const float* zp = Zpart + (size_t)z * CT * NB + base + l;
        float zs = 0.f;
        #pragma unroll 4
        for (int c = w * 40; c < w * 40 + 40; ++c) zs += zp[(size_t)c * NB];
        const float* mp = maxpart + (size_t)z * 128 * NB + base + l;
        const int*   ap = argpart + (size_t)z * 128 * NB + base + l;
        float m = -2.f; int a = 0;
        #pragma unroll 4
        for (int c = w * 32; c < w * 32 + 32; ++c) {
            float v = mp[(size_t)c * NB];
            if (v > m) { m = v; a = ap[(size_t)c * NB]; }
        }
        zls[z][w][l] = zs; mls[z][w][l] = m; als[z][w][l] = a;
    }
    __syncthreads();
    if (t < 128) {
        int z = w;   // 0 or 1
        float zt = zls[z][0][l] + zls[z][1][l] + zls[z][2][l] + zls[z][3][l];
        float mt = mls[z][0][l]; int at = als[z][0][l];
        #pragma unroll
        for (int k = 1; k < 4; ++k)   // ascending c; strict > keeps lowest idx
            if (mls[z][k][l] > mt) { mt = mls[z][k][l]; at = als[z][k][l]; }
        Zr[z][l] = zt; Mr[z][l] = mt; Ar[z][l] = at;
    }
    __syncthreads();

    const int r4 = t >> 2, sub = t & 3;
    const int row = base + r4;
    float d = 0.f, sq1 = 0.f, sq2 = 0.f;
    const float4* x1p = (const float4*)(f1f + (size_t)row * ND);
    const float4* x2p = (const float4*)(f2f + (size_t)row * ND);
    const float4* y1p = (const float4*)(mb2 + (size_t)Ar[0][r4] * ND);
    const float4* y2p = (const float4*)(mb1 + (size_t)Ar[1][r4] * ND);
    #pragma unroll
    for (int k = 0; k < 16; ++k) {
        int idx = k * 4 + sub;
        float4 x1 = x1p[idx], x2 = x2p[idx], y1 = y1p[idx], y2 = y2p[idx];
        d += x1.x*x2.x + x1.y*x2.y + x1.z*x2.z + x1.w*x2.w;
        float dx = x1.x - y1.x, dy = x1.y - y1.y, dz = x1.z - y1.z, dw = x1.w - y1.w;
        sq1 += dx*dx + dy*dy + dz*dz + dw*dw;
        dx = x2.x - y2.x; dy = x2.y - y2.y; dz = x2.z - y2.z; dw = x2.w - y2.w;
        sq2 += dx*dx + dy*dy + dz*dz + dw*dw;
    }
    #pragma unroll
    for (int off = 1; off < 4; off <<= 1) {
        d   += __shfl_xor(d,   off, 4);
        sq1 += __shfl_xor(sq1, off, 4);
        sq2 += __shfl_xor(sq2, off, 4);
    }
    if (sub == 0) {
        float z1 = Zr[0][r4], z2 = Zr[1][r4];
        float ce = logf(z1) + logf(z2) - 2.f * (*scale_ptr) * d;
        bool k1 = Mr[0][r4] > 0.2f, k2 = Mr[1][r4] > 0.2f;
        lds5[r4][0] = ce;
        lds5[r4][1] = k1 ? sq1 : 0.f;
        lds5[r4][2] = k1 ? 1.f : 0.f;
        lds5[r4][3] = k2 ? sq2 : 0.f;
        lds5[r4][4] = k2 ? 1.f : 0.f;
    }
    __syncthreads();
    if (t < 64) {
        float v0 = lds5[t][0], v1 = lds5[t][1], v2 = lds5[t][2],
              v3 = lds5[t][3], v4 = lds5[t][4];
        #pragma unroll
        for (int off = 1; off < 64; off <<= 1) {
            v0 += __shfl_xor(v0, off, 64);
            v1 += __shfl_xor(v1, off, 64);
            v2 += __shfl_xor(v2, off, 64);
            v3 += __shfl_xor(v3, off, 64);
            v4 += __shfl_xor(v4, off, 64);
        }
        if (t == 0) {
            atomicAdd(&accum[0], v0);
            atomicAdd(&accum[1], v1);
            atomicAdd(&accum[2], v2);
            atomicAdd(&accum[3], v3);
            atomicAdd(&accum[4], v4);
            __threadfence();
            int old = atomicAdd((int*)(accum + 5), 1);
            if (old == (int)gridDim.x - 1) {     // last block: combine
                __threadfence();
                float a0 = atomicAdd(&accum[0], 0.f);
                float a1 = atomicAdd(&accum[1], 0.f);
                float a2 = atomicAdd(&accum[2], 0.f);
                float a3 = atomicAdd(&accum[3], 0.f);
                float a4 = atomicAdd(&accum[4], 0.f);
                float nce = 0.5f * a0 / (float)NB;
                float icel1 = a2 > 0.f ? a1 / (a2 * (float)ND) : 0.f;
                float icel2 = a4 > 0.f ? a3 / (a4 * (float)ND) : 0.f;
                out[0] = nce + 0.25f * (icel1 + icel2);   // LAMBDA_ICEL = 0.5
            }
        }
    }
}

extern "C" void kernel_launch(void* const* d_in, const int* in_sizes, int n_in,
                              void* d_out, int out_size, void* d_ws, size_t ws_size,
                              hipStream_t stream) {
    const float* if1   = (const float*)d_in[0];
    const float* if2   = (const float*)d_in[1];
    const float* scale = (const float*)d_in[2];
    const float* mb1   = (const float*)d_in[3];
    const float* mb2   = (const float*)d_in[4];
    float* out = (float*)d_out;

    unsigned char* w = (unsigned char*)d_ws;
    size_t off = 0;
    auto alloc = [&](size_t bytes) {
        void* p = w + off;
        off += (bytes + 255) & ~(size_t)255;
        return p;
    };
    u16*   f1n     = (u16*)  alloc((size_t)NB * ND * 2);
    u16*   f2n     = (u16*)  alloc((size_t)NB * ND * 2);
    u16*   mb1n    = (u16*)  alloc((size_t)NM * ND * 2);
    u16*   mb2n    = (u16*)  alloc((size_t)NM * ND * 2);
    float* f1f     = (float*)alloc((size_t)NB * ND * 4);
    float* f2f     = (float*)alloc((size_t)NB * ND * 4);
    float* Zpart   = (float*)alloc((size_t)2 * CT * NB * 4);
    float* maxpart = (float*)alloc((size_t)2 * 128 * NB * 4);
    int*   argpart = (int*)  alloc((size_t)2 * 128 * NB * 4);
    float* accum   = (float*)alloc(256);

    prep<<<dim3(10240), 256, 0, stream>>>(if1, if2, mb1, mb2,
                                          f1f, f2f, f1n, f2n, mb1n, mb2n, accum);
    gemm_nce<<<dim3(CT, RT, 2), 256, 0, stream>>>(f1n, f2n, mb1n, mb2n, scale,
                                                  Zpart, maxpart, argpart);
    reduce_final<<<dim3(NB / 64), 256, 0, stream>>>(Zpart, maxpart, argpart,
                                                    f1f, f2f, mb1, mb2, scale,
                                                    accum, out);
}

// Round 4
// 237.268 us; speedup vs baseline: 2.5716x; 1.2637x over previous
//
#include <hip/hip_runtime.h>
#include <hip/hip_bf16.h>

typedef unsigned short u16;
typedef float f32x4 __attribute__((ext_vector_type(4)));
typedef __bf16 bf16x8 __attribute__((ext_vector_type(8)));

#define NB 4096     // batch rows
#define NM 16384    // memory bank rows
#define ND 256      // feature dim (K)
#define CT 160      // col tiles (20480 / 128)
#define RT 32       // row tiles (4096 / 128)

__device__ __forceinline__ u16 f2bf(float x) {
    unsigned u = __float_as_uint(x);
    u += 0x7FFF + ((u >> 16) & 1);   // round-to-nearest-even
    return (u16)(u >> 16);
}

__device__ __forceinline__ float ex2(float x) {
#if __has_builtin(__builtin_amdgcn_exp2f)
    return __builtin_amdgcn_exp2f(x);   // single v_exp_f32
#else
    return exp2f(x);
#endif
}

// DPP lane moves within a row of 16 (our reduction group = lane16, q = DPP row)
template<int C>
__device__ __forceinline__ float dppf(float x) {
    int v = __float_as_int(x);
    return __int_as_float(__builtin_amdgcn_update_dpp(v, v, C, 0xF, 0xF, false));
}
template<int C>
__device__ __forceinline__ unsigned dppu(unsigned x) {
    return (unsigned)__builtin_amdgcn_update_dpp((int)x, (int)x, C, 0xF, 0xF, false);
}
#define DPP_XOR1 0xB1   // quad_perm [1,0,3,2]
#define DPP_XOR2 0x4E   // quad_perm [2,3,0,1]
#define DPP_ROR4 0x124  // row_ror:4
#define DPP_ROR8 0x128  // row_ror:8

__device__ __forceinline__ void gld_lds16(const u16* g, u16* l) {
    __builtin_amdgcn_global_load_lds((__attribute__((address_space(1))) void*)g,
                                     (__attribute__((address_space(3))) void*)l,
                                     16, 0, 0);
}

// ---- fused prep: normalize f1/f2 (fp32+bf16 out), convert banks to bf16 ----
__global__ __launch_bounds__(256) void prep(
    const float* __restrict__ if1, const float* __restrict__ if2,
    const float* __restrict__ mb1, const float* __restrict__ mb2,
    float* __restrict__ f1f, float* __restrict__ f2f,
    u16* __restrict__ f1n, u16* __restrict__ f2n,
    u16* __restrict__ mb1n, u16* __restrict__ mb2n,
    float* __restrict__ accum)
{
    const int b = blockIdx.x, t = threadIdx.x;
    if (b == 0 && t < 8) accum[t] = 0.f;   // zero sums + counter
    if (b < 2048) {
        const int wave = t >> 6, lane = t & 63;
        const int g = b * 4 + wave;         // 0..8191
        const float* in; float* of; u16* ob; int row;
        if (g < NB) { in = if1; of = f1f; ob = f1n; row = g; }
        else        { in = if2; of = f2f; ob = f2n; row = g - NB; }
        float4 v = ((const float4*)(in + (size_t)row * ND))[lane];
        float ss = v.x*v.x + v.y*v.y + v.z*v.z + v.w*v.w;
        #pragma unroll
        for (int off = 1; off < 64; off <<= 1) ss += __shfl_xor(ss, off, 64);
        float inv = 1.0f / fmaxf(sqrtf(ss), 1e-12f);
        float4 o = make_float4(v.x*inv, v.y*inv, v.z*inv, v.w*inv);
        ((float4*)(of + (size_t)row * ND))[lane] = o;
        ushort4 bb = make_ushort4(f2bf(o.x), f2bf(o.y), f2bf(o.z), f2bf(o.w));
        ((ushort4*)(ob + (size_t)row * ND))[lane] = bb;
    } else {
        size_t i = (size_t)(b - 2048) * 256 + t;      // float4 index
        const float* in; u16* ob; size_t idx;
        if (i < (size_t)NM * 64) { in = mb1; ob = mb1n; idx = i; }
        else { in = mb2; ob = mb2n; idx = i - (size_t)NM * 64; }
        float4 v = ((const float4*)in)[idx];
        ushort4 bb = make_ushort4(f2bf(v.x), f2bf(v.y), f2bf(v.z), f2bf(v.w));
        ((ushort4*)ob)[idx] = bb;
    }
}

// ---- fused GEMM + (sum-exp, packed max/argmax) epilogue --------------------
// grid: (160 coltiles, 32 rowtiles, 2 matmuls), block 256 (4 waves, 2x2)
// LDS XOR-swizzled: chunk at (row, slot cs) holds global chunk cs ^ (row&7).
__global__ __launch_bounds__(256) void gemm_nce(
    const u16* __restrict__ f1n, const u16* __restrict__ f2n,
    const u16* __restrict__ mb1n, const u16* __restrict__ mb2n,
    const float* __restrict__ scale_ptr,
    float* __restrict__ Zpart,    // [2][CT][NB]
    float* __restrict__ maxpart,  // [2][128][NB]
    int*   __restrict__ argpart)  // [2][128][NB]
{
    __shared__ __attribute__((aligned(16))) u16 As[128 * 64];
    __shared__ __attribute__((aligned(16))) u16 Bs[128 * 64];
    __shared__ float    redsum[2][128];
    __shared__ unsigned redpak[2][128];

    const int ctile = blockIdx.x, rtile = blockIdx.y, z = blockIdx.z;
    const u16* A  = (z ? f2n : f1n) + (size_t)rtile * 128 * ND;
    const u16* Bp = (ctile < 32) ? ((z ? f1n : f2n) + (size_t)ctile * 128 * ND)
                                 : ((z ? mb1n : mb2n) + (size_t)(ctile - 32) * 128 * ND);
    const int t = threadIdx.x;
    const int wave = t >> 6, lane = t & 63;
    const int wr = wave >> 1, wc = wave & 1;
    const int lane16 = lane & 15, q = lane >> 4;
    const int srow = t >> 3;                        // 0..31 staged row
    const int cg = (t & 7) ^ ((t >> 3) & 7);        // swizzled global chunk

    f32x4 acc[4][4] = {};

    #pragma unroll
    for (int kt = 0; kt < 4; ++kt) {
        const u16* ga = A  + (size_t)srow * ND + kt * 64 + cg * 8;
        const u16* gb = Bp + (size_t)srow * ND + kt * 64 + cg * 8;
        u16* la = As + t * 8;
        u16* lb = Bs + t * 8;
        #pragma unroll
        for (int ch = 0; ch < 4; ++ch) {
            gld_lds16(ga + (size_t)ch * 32 * ND, la + ch * 2048);
            gld_lds16(gb + (size_t)ch * 32 * ND, lb + ch * 2048);
        }
        __syncthreads();   // drains vmcnt (global_load_lds) before LDS reads
        #pragma unroll
        for (int kk = 0; kk < 2; ++kk) {
            bf16x8 af[4], bfr[4];
            const int sw = (kk * 4 + q) ^ (lane16 & 7);   // swizzled chunk slot
            #pragma unroll
            for (int i = 0; i < 4; ++i)
                af[i] = *(const bf16x8*)(As + (wr*64 + i*16 + lane16)*64 + sw*8);
            #pragma unroll
            for (int j = 0; j < 4; ++j)
                bfr[j] = *(const bf16x8*)(Bs + (wc*64 + j*16 + lane16)*64 + sw*8);
            #pragma unroll
            for (int i = 0; i < 4; ++i)
                #pragma unroll
                for (int j = 0; j < 4; ++j)
                    acc[i][j] = __builtin_amdgcn_mfma_f32_16x16x32_bf16(
                        af[i], bfr[j], acc[i][j], 0, 0, 0);
        }
        __syncthreads();
    }

    const float scale = *scale_ptr;
    const float kl = scale * 1.44269504088896f;  // scale * log2(e)
    const bool doicel = (ctile >= 32);

    // Pack: positive IEEE floats are bit-order-isomorphic to value, so
    // packed = (bits(t + 21) << 7) | (127 - col) compares by value first
    // (truncated to 16 mantissa bits), then LOWER column on ties.
    unsigned cpack[4];
    #pragma unroll
    for (int j = 0; j < 4; ++j) cpack[j] = 127 - (j * 16 + lane16);

    // C/D layout (m89/m91): col = lane&15, row = q*4 + reg (within 16x16)
    #pragma unroll
    for (int i = 0; i < 4; ++i) {
        #pragma unroll
        for (int r = 0; r < 4; ++r) {
            float t0 = kl * acc[i][0][r], t1 = kl * acc[i][1][r],
                  t2 = kl * acc[i][2][r], t3 = kl * acc[i][3][r];
            float e = (ex2(t0) + ex2(t1)) + (ex2(t2) + ex2(t3));
            e += dppf<DPP_XOR1>(e);
            e += dppf<DPP_XOR2>(e);
            e += dppf<DPP_ROR4>(e);
            e += dppf<DPP_ROR8>(e);
            unsigned p = 0;
            if (doicel) {
                unsigned p0 = (__float_as_uint(t0 + 21.f) << 7) | cpack[0];
                unsigned p1 = (__float_as_uint(t1 + 21.f) << 7) | cpack[1];
                unsigned p2 = (__float_as_uint(t2 + 21.f) << 7) | cpack[2];
                unsigned p3 = (__float_as_uint(t3 + 21.f) << 7) | cpack[3];
                p = max(max(p0, p1), max(p2, p3));
                p = max(p, dppu<DPP_XOR1>(p));
                p = max(p, dppu<DPP_XOR2>(p));
                p = max(p, dppu<DPP_ROR4>(p));
                p = max(p, dppu<DPP_ROR8>(p));
            }
            if (lane16 == 0) {
                int rl = wr*64 + i*16 + q*4 + r;
                redsum[wc][rl] = e;
                redpak[wc][rl] = p;
            }
        }
    }
    __syncthreads();
    if (t < 128) {
        int grow = rtile * 128 + t;
        float zs = redsum[0][t] + redsum[1][t];
        Zpart[((size_t)z * CT + ctile) * NB + grow] = zs;   // coalesced over t
        if (ctile >= 32) {
            unsigned q0 = redpak[0][t], q1 = redpak[1][t];
            float t0 = __uint_as_float(q0 & 0xFFFFFF80u) - 21.f;  // kl-scaled
            float t1 = __uint_as_float(q1 & 0xFFFFFF80u) - 21.f;
            int c0 = 127 - (int)(q0 & 127);   // 0..63 within wc half
            int c1 = 127 - (int)(q1 & 127);
            float m = t0; int a = c0;
            if (t1 > m) { m = t1; a = 64 + c1; }  // strict >: tie keeps lower col
            size_t idx = ((size_t)z * 128 + (ctile - 32)) * NB + grow;
            maxpart[idx] = m / kl;               // back to cosine-sim units
            argpart[idx] = (ctile - 32) * 128 + a;
        }
    }
}

// ---- fused reduce + finalize + combine (single launch, atomic counter) -----
// grid 64 blocks x 256: block handles 64 rows for BOTH z.
__global__ __launch_bounds__(256) void reduce_final(
    const float* __restrict__ Zpart, const float* __restrict__ maxpart,
    const int* __restrict__ argpart,
    const float* __restrict__ f1f, const float* __restrict__ f2f,
    const float* __restrict__ mb1, const float* __restrict__ mb2,
    const float* __restrict__ scale_ptr, float* __restrict__ accum,
    float* __restrict__ out)
{
    __shared__ float zls[2][4][64];
    __shared__ float mls[2][4][64];
    __shared__ int   als[2][4][64];
    __shared__ float Zr[2][64], Mr[2][64];
    __shared__ int   Ar[2][64];
    __shared__ float lds5[64][5];

    const int t = threadIdx.x, w = t >> 6, l = t & 63;
    const int base = blockIdx.x * 64;

    #pragma unroll
    for (int z = 0; z < 2; ++z) {
        const float* zp = Zpart + (size_t)z * CT * NB + base + l;
        float zs = 0.f;
        #pragma unroll 4
        for (int c = w * 40; c < w * 40 + 40; ++c) zs += zp[(size_t)c * NB];
        const float* mp = maxpart + (size_t)z * 128 * NB + base + l;
        const int*   ap = argpart + (size_t)z * 128 * NB + base + l;
        float m = -2.f; int a = 0;
        #pragma unroll 4
        for (int c = w * 32; c < w * 32 + 32; ++c) {
            float v = mp[(size_t)c * NB];
            if (v > m) { m = v; a = ap[(size_t)c * NB]; }
        }
        zls[z][w][l] = zs; mls[z][w][l] = m; als[z][w][l] = a;
    }
    __syncthreads();
    if (t < 128) {
        int z = w;   // 0 or 1
        float zt = zls[z][0][l] + zls[z][1][l] + zls[z][2][l] + zls[z][3][l];
        float mt = mls[z][0][l]; int at = als[z][0][l];
        #pragma unroll
        for (int k = 1; k < 4; ++k)   // ascending c; strict > keeps lowest idx
            if (mls[z][k][l] > mt) { mt = mls[z][k][l]; at = als[z][k][l]; }
        Zr[z][l] = zt; Mr[z][l] = mt; Ar[z][l] = at;
    }
    __syncthreads();

    const int r4 = t >> 2, sub = t & 3;
    const int row = base + r4;
    float d = 0.f, sq1 = 0.f, sq2 = 0.f;
    const float4* x1p = (const float4*)(f1f + (size_t)row * ND);
    const float4* x2p = (const float4*)(f2f + (size_t)row * ND);
    const float4* y1p = (const float4*)(mb2 + (size_t)Ar[0][r4] * ND);
    const float4* y2p = (const float4*)(mb1 + (size_t)Ar[1][r4] * ND);
    #pragma unroll
    for (int k = 0; k < 16; ++k) {
        int idx = k * 4 + sub;
        float4 x1 = x1p[idx], x2 = x2p[idx], y1 = y1p[idx], y2 = y2p[idx];
        d += x1.x*x2.x + x1.y*x2.y + x1.z*x2.z + x1.w*x2.w;
        float dx = x1.x - y1.x, dy = x1.y - y1.y, dz = x1.z - y1.z, dw = x1.w - y1.w;
        sq1 += dx*dx + dy*dy + dz*dz + dw*dw;
        dx = x2.x - y2.x; dy = x2.y - y2.y; dz = x2.z - y2.z; dw = x2.w - y2.w;
        sq2 += dx*dx + dy*dy + dz*dz + dw*dw;
    }
    #pragma unroll
    for (int off = 1; off < 4; off <<= 1) {
        d   += __shfl_xor(d,   off, 4);
        sq1 += __shfl_xor(sq1, off, 4);
        sq2 += __shfl_xor(sq2, off, 4);
    }
    if (sub == 0) {
        float z1 = Zr[0][r4], z2 = Zr[1][r4];
        float ce = logf(z1) + logf(z2) - 2.f * (*scale_ptr) * d;
        bool k1 = Mr[0][r4] > 0.2f, k2 = Mr[1][r4] > 0.2f;
        lds5[r4][0] = ce;
        lds5[r4][1] = k1 ? sq1 : 0.f;
        lds5[r4][2] = k1 ? 1.f : 0.f;
        lds5[r4][3] = k2 ? sq2 : 0.f;
        lds5[r4][4] = k2 ? 1.f : 0.f;
    }
    __syncthreads();
    if (t < 64) {
        float v0 = lds5[t][0], v1 = lds5[t][1], v2 = lds5[t][2],
              v3 = lds5[t][3], v4 = lds5[t][4];
        #pragma unroll
        for (int off = 1; off < 64; off <<= 1) {
            v0 += __shfl_xor(v0, off, 64);
            v1 += __shfl_xor(v1, off, 64);
            v2 += __shfl_xor(v2, off, 64);
            v3 += __shfl_xor(v3, off, 64);
            v4 += __shfl_xor(v4, off, 64);
        }
        if (t == 0) {
            atomicAdd(&accum[0], v0);
            atomicAdd(&accum[1], v1);
            atomicAdd(&accum[2], v2);
            atomicAdd(&accum[3], v3);
            atomicAdd(&accum[4], v4);
            __threadfence();
            int old = atomicAdd((int*)(accum + 5), 1);
            if (old == (int)gridDim.x - 1) {     // last block: combine
                __threadfence();
                float a0 = atomicAdd(&accum[0], 0.f);
                float a1 = atomicAdd(&accum[1], 0.f);
                float a2 = atomicAdd(&accum[2], 0.f);
                float a3 = atomicAdd(&accum[3], 0.f);
                float a4 = atomicAdd(&accum[4], 0.f);
                float nce = 0.5f * a0 / (float)NB;
                float icel1 = a2 > 0.f ? a1 / (a2 * (float)ND) : 0.f;
                float icel2 = a4 > 0.f ? a3 / (a4 * (float)ND) : 0.f;
                out[0] = nce + 0.25f * (icel1 + icel2);   // LAMBDA_ICEL = 0.5
            }
        }
    }
}

extern "C" void kernel_launch(void* const* d_in, const int* in_sizes, int n_in,
                              void* d_out, int out_size, void* d_ws, size_t ws_size,
                              hipStream_t stream) {
    const float* if1   = (const float*)d_in[0];
    const float* if2   = (const float*)d_in[1];
    const float* scale = (const float*)d_in[2];
    const float* mb1   = (const float*)d_in[3];
    const float* mb2   = (const float*)d_in[4];
    float* out = (float*)d_out;

    unsigned char* w = (unsigned char*)d_ws;
    size_t off = 0;
    auto alloc = [&](size_t bytes) {
        void* p = w + off;
        off += (bytes + 255) & ~(size_t)255;
        return p;
    };
    u16*   f1n     = (u16*)  alloc((size_t)NB * ND * 2);
    u16*   f2n     = (u16*)  alloc((size_t)NB * ND * 2);
    u16*   mb1n    = (u16*)  alloc((size_t)NM * ND * 2);
    u16*   mb2n    = (u16*)  alloc((size_t)NM * ND * 2);
    float* f1f     = (float*)alloc((size_t)NB * ND * 4);
    float* f2f     = (float*)alloc((size_t)NB * ND * 4);
    float* Zpart   = (float*)alloc((size_t)2 * CT * NB * 4);
    float* maxpart = (float*)alloc((size_t)2 * 128 * NB * 4);
    int*   argpart = (int*)  alloc((size_t)2 * 128 * NB * 4);
    float* accum   = (float*)alloc(256);

    prep<<<dim3(10240), 256, 0, stream>>>(if1, if2, mb1, mb2,
                                          f1f, f2f, f1n, f2n, mb1n, mb2n, accum);
    gemm_nce<<<dim3(CT, RT, 2), 256, 0, stream>>>(f1n, f2n, mb1n, mb2n, scale,
                                                  Zpart, maxpart, argpart);
    reduce_final<<<dim3(NB / 64), 256, 0, stream>>>(Zpart, maxpart, argpart,
                                                    f1f, f2f, mb1, mb2, scale,
                                                    accum, out);
}

// Round 5
// 218.729 us; speedup vs baseline: 2.7895x; 1.0848x over previous
//
#include <hip/hip_runtime.h>
#include <hip/hip_bf16.h>

typedef unsigned short u16;
typedef float f32x4 __attribute__((ext_vector_type(4)));
typedef __bf16 bf16x8 __attribute__((ext_vector_type(8)));

#define NB 4096     // batch rows
#define NM 16384    // memory bank rows
#define ND 256      // feature dim (K)
#define CT 160      // col tiles (20480 / 128)
#define RT 32       // row tiles (4096 / 128)

__device__ __forceinline__ u16 f2bf(float x) {
    unsigned u = __float_as_uint(x);
    u += 0x7FFF + ((u >> 16) & 1);   // round-to-nearest-even
    return (u16)(u >> 16);
}

__device__ __forceinline__ float ex2(float x) {
#if __has_builtin(__builtin_amdgcn_exp2f)
    return __builtin_amdgcn_exp2f(x);   // single v_exp_f32
#else
    return exp2f(x);
#endif
}

// DPP lane moves within a row of 16 (our reduction group = lane16, q = DPP row)
template<int C>
__device__ __forceinline__ float dppf(float x) {
    int v = __float_as_int(x);
    return __int_as_float(__builtin_amdgcn_update_dpp(v, v, C, 0xF, 0xF, false));
}
template<int C>
__device__ __forceinline__ unsigned dppu(unsigned x) {
    return (unsigned)__builtin_amdgcn_update_dpp((int)x, (int)x, C, 0xF, 0xF, false);
}
#define DPP_XOR1 0xB1   // quad_perm [1,0,3,2]
#define DPP_XOR2 0x4E   // quad_perm [2,3,0,1]
#define DPP_ROR4 0x124  // row_ror:4
#define DPP_ROR8 0x128  // row_ror:8

__device__ __forceinline__ void gld_lds16(const u16* g, u16* l) {
    __builtin_amdgcn_global_load_lds((__attribute__((address_space(1))) void*)g,
                                     (__attribute__((address_space(3))) void*)l,
                                     16, 0, 0);
}

// ---- fused prep: normalize f1/f2 (fp32+bf16 out), convert banks to bf16 ----
__global__ __launch_bounds__(256) void prep(
    const float* __restrict__ if1, const float* __restrict__ if2,
    const float* __restrict__ mb1, const float* __restrict__ mb2,
    float* __restrict__ f1f, float* __restrict__ f2f,
    u16* __restrict__ f1n, u16* __restrict__ f2n,
    u16* __restrict__ mb1n, u16* __restrict__ mb2n,
    float* __restrict__ accum)
{
    const int b = blockIdx.x, t = threadIdx.x;
    if (b == 0 && t < 8) accum[t] = 0.f;   // zero sums + counter
    if (b < 2048) {
        const int wave = t >> 6, lane = t & 63;
        const int g = b * 4 + wave;         // 0..8191
        const float* in; float* of; u16* ob; int row;
        if (g < NB) { in = if1; of = f1f; ob = f1n; row = g; }
        else        { in = if2; of = f2f; ob = f2n; row = g - NB; }
        float4 v = ((const float4*)(in + (size_t)row * ND))[lane];
        float ss = v.x*v.x + v.y*v.y + v.z*v.z + v.w*v.w;
        #pragma unroll
        for (int off = 1; off < 64; off <<= 1) ss += __shfl_xor(ss, off, 64);
        float inv = 1.0f / fmaxf(sqrtf(ss), 1e-12f);
        float4 o = make_float4(v.x*inv, v.y*inv, v.z*inv, v.w*inv);
        ((float4*)(of + (size_t)row * ND))[lane] = o;
        ushort4 bb = make_ushort4(f2bf(o.x), f2bf(o.y), f2bf(o.z), f2bf(o.w));
        ((ushort4*)(ob + (size_t)row * ND))[lane] = bb;
    } else {
        size_t i = (size_t)(b - 2048) * 256 + t;      // float4 index
        const float* in; u16* ob; size_t idx;
        if (i < (size_t)NM * 64) { in = mb1; ob = mb1n; idx = i; }
        else { in = mb2; ob = mb2n; idx = i - (size_t)NM * 64; }
        float4 v = ((const float4*)in)[idx];
        ushort4 bb = make_ushort4(f2bf(v.x), f2bf(v.y), f2bf(v.z), f2bf(v.w));
        ((ushort4*)ob)[idx] = bb;
    }
}

// ---- fused GEMM + (sum-exp, packed max/argmax) epilogue --------------------
// grid: (160 coltiles, 32 rowtiles, 2 matmuls), block 256 (4 waves, 2x2)
// LDS XOR-swizzled: chunk at (row, slot cs) holds global chunk cs ^ (row&7).
// launch_bounds(256,4): request 4 waves/EU -> 4 blocks/CU (VGPR budget 128).
__global__ __launch_bounds__(256, 4) void gemm_nce(
    const u16* __restrict__ f1n, const u16* __restrict__ f2n,
    const u16* __restrict__ mb1n, const u16* __restrict__ mb2n,
    const float* __restrict__ scale_ptr,
    float* __restrict__ Zpart,    // [2][CT][NB]
    float* __restrict__ maxpart,  // [2][128][NB]
    int*   __restrict__ argpart)  // [2][128][NB]
{
    __shared__ __attribute__((aligned(16))) u16 As[128 * 64];
    __shared__ __attribute__((aligned(16))) u16 Bs[128 * 64];
    __shared__ float    redsum[2][128];
    __shared__ unsigned redpak[2][128];

    const int ctile = blockIdx.x, rtile = blockIdx.y, z = blockIdx.z;
    const u16* A  = (z ? f2n : f1n) + (size_t)rtile * 128 * ND;
    const u16* Bp = (ctile < 32) ? ((z ? f1n : f2n) + (size_t)ctile * 128 * ND)
                                 : ((z ? mb1n : mb2n) + (size_t)(ctile - 32) * 128 * ND);
    const int t = threadIdx.x;
    const int wave = t >> 6, lane = t & 63;
    const int wr = wave >> 1, wc = wave & 1;
    const int lane16 = lane & 15, q = lane >> 4;
    const int srow = t >> 3;                        // 0..31 staged row
    const int cg = (t & 7) ^ ((t >> 3) & 7);        // swizzled global chunk

    f32x4 acc[4][4] = {};

    #pragma unroll
    for (int kt = 0; kt < 4; ++kt) {
        const u16* ga = A  + (size_t)srow * ND + kt * 64 + cg * 8;
        const u16* gb = Bp + (size_t)srow * ND + kt * 64 + cg * 8;
        u16* la = As + t * 8;
        u16* lb = Bs + t * 8;
        #pragma unroll
        for (int ch = 0; ch < 4; ++ch) {
            gld_lds16(ga + (size_t)ch * 32 * ND, la + ch * 2048);
            gld_lds16(gb + (size_t)ch * 32 * ND, lb + ch * 2048);
        }
        __syncthreads();   // drains vmcnt (global_load_lds) before LDS reads
        #pragma unroll
        for (int kk = 0; kk < 2; ++kk) {
            bf16x8 af[4], bfr[4];
            const int sw = (kk * 4 + q) ^ (lane16 & 7);   // swizzled chunk slot
            #pragma unroll
            for (int i = 0; i < 4; ++i)
                af[i] = *(const bf16x8*)(As + (wr*64 + i*16 + lane16)*64 + sw*8);
            #pragma unroll
            for (int j = 0; j < 4; ++j)
                bfr[j] = *(const bf16x8*)(Bs + (wc*64 + j*16 + lane16)*64 + sw*8);
            #pragma unroll
            for (int i = 0; i < 4; ++i)
                #pragma unroll
                for (int j = 0; j < 4; ++j)
                    acc[i][j] = __builtin_amdgcn_mfma_f32_16x16x32_bf16(
                        af[i], bfr[j], acc[i][j], 0, 0, 0);
        }
        __syncthreads();
    }

    const float scale = *scale_ptr;
    const float kl = scale * 1.44269504088896f;  // scale * log2(e)
    const bool doicel = (ctile >= 32);

    // Pack: positive IEEE floats are bit-order-isomorphic to value, so
    // packed = (bits(t + 21) << 7) | (127 - col) compares by value first
    // (truncated), then LOWER column on ties.
    unsigned cpack[4];
    #pragma unroll
    for (int j = 0; j < 4; ++j) cpack[j] = 127 - (j * 16 + lane16);

    // C/D layout (m89/m91): col = lane&15, row = q*4 + reg (within 16x16)
    #pragma unroll
    for (int i = 0; i < 4; ++i) {
        #pragma unroll
        for (int r = 0; r < 4; ++r) {
            float t0 = kl * acc[i][0][r], t1 = kl * acc[i][1][r],
                  t2 = kl * acc[i][2][r], t3 = kl * acc[i][3][r];
            float e = (ex2(t0) + ex2(t1)) + (ex2(t2) + ex2(t3));
            e += dppf<DPP_XOR1>(e);
            e += dppf<DPP_XOR2>(e);
            e += dppf<DPP_ROR4>(e);
            e += dppf<DPP_ROR8>(e);
            unsigned p = 0;
            if (doicel) {
                unsigned p0 = (__float_as_uint(t0 + 21.f) << 7) | cpack[0];
                unsigned p1 = (__float_as_uint(t1 + 21.f) << 7) | cpack[1];
                unsigned p2 = (__float_as_uint(t2 + 21.f) << 7) | cpack[2];
                unsigned p3 = (__float_as_uint(t3 + 21.f) << 7) | cpack[3];
                p = max(max(p0, p1), max(p2, p3));
                p = max(p, dppu<DPP_XOR1>(p));
                p = max(p, dppu<DPP_XOR2>(p));
                p = max(p, dppu<DPP_ROR4>(p));
                p = max(p, dppu<DPP_ROR8>(p));
            }
            if (lane16 == 0) {
                int rl = wr*64 + i*16 + q*4 + r;
                redsum[wc][rl] = e;
                redpak[wc][rl] = p;
            }
        }
    }
    __syncthreads();
    if (t < 128) {
        int grow = rtile * 128 + t;
        float zs = redsum[0][t] + redsum[1][t];
        Zpart[((size_t)z * CT + ctile) * NB + grow] = zs;   // coalesced over t
        if (ctile >= 32) {
            unsigned q0 = redpak[0][t], q1 = redpak[1][t];
            float t0 = __uint_as_float(q0 & 0xFFFFFF80u) - 21.f;  // kl-scaled
            float t1 = __uint_as_float(q1 & 0xFFFFFF80u) - 21.f;
            int c0 = 127 - (int)(q0 & 127);   // 0..63 within wc half
            int c1 = 127 - (int)(q1 & 127);
            float m = t0; int a = c0;
            if (t1 > m) { m = t1; a = 64 + c1; }  // strict >: tie keeps lower col
            size_t idx = ((size_t)z * 128 + (ctile - 32)) * NB + grow;
            maxpart[idx] = m / kl;               // back to cosine-sim units
            argpart[idx] = (ctile - 32) * 128 + a;
        }
    }
}

// ---- reduce + finalize + combine, v2: 128 blocks x 1024 threads ------------
// block = (z, 64-row group). Phase 1: coalesced Z/max reduce over col tiles.
// Phase 2: 16 lanes/row gather + MSE (+ diag dot for z=0). Atomic combine.
__global__ __launch_bounds__(1024) void reduce_final2(
    const float* __restrict__ Zpart, const float* __restrict__ maxpart,
    const int* __restrict__ argpart,
    const float* __restrict__ f1f, const float* __restrict__ f2f,
    const float* __restrict__ mb1, const float* __restrict__ mb2,
    const float* __restrict__ scale_ptr, float* __restrict__ accum,
    float* __restrict__ out)
{
    __shared__ float zls[16][64];
    __shared__ float mls[16][64];
    __shared__ int   als[16][64];
    __shared__ float Zr[64], Mr[64];
    __shared__ int   Ar[64];
    __shared__ float p_lz[64], p_sq[64], p_cnt[64], p_d[64];

    const int t = threadIdx.x, w = t >> 6, l = t & 63;
    const int z = blockIdx.x & 1, rg = blockIdx.x >> 1;
    const int base = rg * 64;

    {   // Z partials: wave w covers 10 of 160 cols, lanes along rows (coalesced)
        const float* zp = Zpart + (size_t)z * CT * NB + base + l;
        float zs = 0.f;
        #pragma unroll
        for (int c = w * 10; c < w * 10 + 10; ++c) zs += zp[(size_t)c * NB];
        zls[w][l] = zs;
    }
    {   // max partials: wave w covers 8 of 128 cols
        const float* mp = maxpart + (size_t)z * 128 * NB + base + l;
        const int*   ap = argpart + (size_t)z * 128 * NB + base + l;
        float m = -2.f; int a = 0;
        #pragma unroll
        for (int c = w * 8; c < w * 8 + 8; ++c) {
            float v = mp[(size_t)c * NB];
            if (v > m) { m = v; a = ap[(size_t)c * NB]; }
        }
        mls[w][l] = m; als[w][l] = a;
    }
    __syncthreads();
    if (t < 64) {
        float zt = 0.f;
        #pragma unroll
        for (int k = 0; k < 16; ++k) zt += zls[k][l];
        float mt = mls[0][l]; int at = als[0][l];
        #pragma unroll
        for (int k = 1; k < 16; ++k)   // ascending col ranges; strict > keeps lowest
            if (mls[k][l] > mt) { mt = mls[k][l]; at = als[k][l]; }
        Zr[l] = zt; Mr[l] = mt; Ar[l] = at;
    }
    __syncthreads();

    // Phase 2: 16 lanes per row (64 rows, 1024 threads)
    const int g = t >> 4, l16 = t & 15;
    const int row = base + g;
    const float* fz = (z ? f2f : f1f) + (size_t)row * ND;
    const float* fo = (z ? f1f : f2f) + (size_t)row * ND;
    const float* bank = (z ? mb1 : mb2);
    const float* y = bank + (size_t)Ar[g] * ND;
    float sq = 0.f, d = 0.f;
    #pragma unroll
    for (int k = 0; k < 4; ++k) {
        int idx = k * 16 + l16;
        float4 x  = ((const float4*)fz)[idx];
        float4 yy = ((const float4*)y)[idx];
        float dx = x.x-yy.x, dy = x.y-yy.y, dz = x.z-yy.z, dw = x.w-yy.w;
        sq += dx*dx + dy*dy + dz*dz + dw*dw;
        if (z == 0) {   // block-uniform branch
            float4 o = ((const float4*)fo)[idx];
            d += x.x*o.x + x.y*o.y + x.z*o.z + x.w*o.w;
        }
    }
    #pragma unroll
    for (int off = 1; off < 16; off <<= 1) {
        sq += __shfl_xor(sq, off, 16);
        d  += __shfl_xor(d,  off, 16);
    }
    if (l16 == 0) {
        bool msk = Mr[g] > 0.2f;
        p_lz[g]  = logf(Zr[g]);
        p_sq[g]  = msk ? sq : 0.f;
        p_cnt[g] = msk ? 1.f : 0.f;
        p_d[g]   = d;                 // zero for z==1
    }
    __syncthreads();
    if (t < 64) {
        float v0 = p_lz[t], v1 = p_sq[t], v2 = p_cnt[t], v3 = p_d[t];
        #pragma unroll
        for (int off = 1; off < 64; off <<= 1) {
            v0 += __shfl_xor(v0, off, 64);
            v1 += __shfl_xor(v1, off, 64);
            v2 += __shfl_xor(v2, off, 64);
            v3 += __shfl_xor(v3, off, 64);
        }
        if (t == 0) {
            atomicAdd(&accum[0], v0);               // sum of log Z (both z)
            atomicAdd(&accum[z ? 3 : 1], v1);       // masked sq sums
            atomicAdd(&accum[z ? 4 : 2], v2);       // masked counts
            if (z == 0) atomicAdd(&accum[5], v3);   // sum of diag dots
            __threadfence();
            int old = atomicAdd((int*)(accum + 6), 1);
            if (old == (int)gridDim.x - 1) {        // last block: combine
                __threadfence();
                float a0 = atomicAdd(&accum[0], 0.f);
                float a1 = atomicAdd(&accum[1], 0.f);
                float a2 = atomicAdd(&accum[2], 0.f);
                float a3 = atomicAdd(&accum[3], 0.f);
                float a4 = atomicAdd(&accum[4], 0.f);
                float a5 = atomicAdd(&accum[5], 0.f);
                float nce = 0.5f * (a0 - 2.f * (*scale_ptr) * a5) / (float)NB;
                float icel1 = a2 > 0.f ? a1 / (a2 * (float)ND) : 0.f;
                float icel2 = a4 > 0.f ? a3 / (a4 * (float)ND) : 0.f;
                out[0] = nce + 0.25f * (icel1 + icel2);   // LAMBDA_ICEL = 0.5
            }
        }
    }
}

extern "C" void kernel_launch(void* const* d_in, const int* in_sizes, int n_in,
                              void* d_out, int out_size, void* d_ws, size_t ws_size,
                              hipStream_t stream) {
    const float* if1   = (const float*)d_in[0];
    const float* if2   = (const float*)d_in[1];
    const float* scale = (const float*)d_in[2];
    const float* mb1   = (const float*)d_in[3];
    const float* mb2   = (const float*)d_in[4];
    float* out = (float*)d_out;

    unsigned char* w = (unsigned char*)d_ws;
    size_t off = 0;
    auto alloc = [&](size_t bytes) {
        void* p = w + off;
        off += (bytes + 255) & ~(size_t)255;
        return p;
    };
    u16*   f1n     = (u16*)  alloc((size_t)NB * ND * 2);
    u16*   f2n     = (u16*)  alloc((size_t)NB * ND * 2);
    u16*   mb1n    = (u16*)  alloc((size_t)NM * ND * 2);
    u16*   mb2n    = (u16*)  alloc((size_t)NM * ND * 2);
    float* f1f     = (float*)alloc((size_t)NB * ND * 4);
    float* f2f     = (float*)alloc((size_t)NB * ND * 4);
    float* Zpart   = (float*)alloc((size_t)2 * CT * NB * 4);
    float* maxpart = (float*)alloc((size_t)2 * 128 * NB * 4);
    int*   argpart = (int*)  alloc((size_t)2 * 128 * NB * 4);
    float* accum   = (float*)alloc(256);

    prep<<<dim3(10240), 256, 0, stream>>>(if1, if2, mb1, mb2,
                                          f1f, f2f, f1n, f2n, mb1n, mb2n, accum);
    gemm_nce<<<dim3(CT, RT, 2), 256, 0, stream>>>(f1n, f2n, mb1n, mb2n, scale,
                                                  Zpart, maxpart, argpart);
    reduce_final2<<<dim3(128), 1024, 0, stream>>>(Zpart, maxpart, argpart,
                                                  f1f, f2f, mb1, mb2, scale,
                                                  accum, out);
}